// Round 3
// baseline (355.285 us; speedup 1.0000x reference)
//
#include <hip/hip_runtime.h>
#include <math.h>

#define LOG_EPS   (-18.420680743952367f)   // ln(1e-8)
#define LOG_INV_K (-2.772588722239781f)    // ln(1/16)

// ---------------------------------------------------------------------------
// Kernel A: blocks 0..31 -> W_eff = W_slot @ W_fusion, b_eff
//           block  32    -> G softmax+sinkhorn+zero-diag + Frobenius reg
// ---------------------------------------------------------------------------
__global__ void kA(const float* __restrict__ W_fusion, const float* __restrict__ b_fusion,
                   const float* __restrict__ W_slot,   const float* __restrict__ b_slot,
                   const float* __restrict__ G_param,
                   float* __restrict__ W_eff, float* __restrict__ b_eff,
                   float* __restrict__ G_out, float* __restrict__ out_reg) {
    int t = threadIdx.x;
    if (blockIdx.x < 32) {
        int idx = blockIdx.x * 256 + t;          // 0..8191
        int k = idx >> 9, j = idx & 511;
        const float* ws = W_slot + k * 256;
        float s = 0.f;
        #pragma unroll 4
        for (int d = 0; d < 256; ++d) s += ws[d] * W_fusion[d * 512 + j];
        W_eff[idx] = s;
        if (idx < 16) {
            float bb = b_slot[idx];
            for (int d = 0; d < 256; ++d) bb += W_slot[idx * 256 + d] * b_fusion[d];
            b_eff[idx] = bb;
        }
        return;
    }
    // ---- G block ----
    __shared__ float M[2048];
    __shared__ float red[256];
    __shared__ float inv_nrm[8];
    __shared__ float hsq[8];
    __shared__ float trace_s;

    if (t < 128) {
        int base = t * 16;
        float v[16]; float mx = -1e30f;
        #pragma unroll
        for (int l = 0; l < 16; ++l) { v[l] = G_param[base + l]; mx = fmaxf(mx, v[l]); }
        float s = 0.f;
        #pragma unroll
        for (int l = 0; l < 16; ++l) { v[l] = expf(v[l] - mx); s += v[l]; }
        float r = 1.f / s;
        #pragma unroll
        for (int l = 0; l < 16; ++l) M[base + l] = fmaxf(v[l] * r, 1e-6f);
    }
    __syncthreads();
    for (int it = 0; it < 10; ++it) {
        if (t < 128) {
            float s = 0.f;
            #pragma unroll
            for (int l = 0; l < 16; ++l) s += M[t * 16 + l];
            float r = 1.f / (s + 1e-6f);
            #pragma unroll
            for (int l = 0; l < 16; ++l) M[t * 16 + l] *= r;
        }
        __syncthreads();
        if (t < 128) {
            int h = t >> 4, l = t & 15, base = h * 256 + l;
            float s = 0.f;
            #pragma unroll
            for (int k = 0; k < 16; ++k) s += M[base + k * 16];
            float r = 1.f / (s + 1e-6f);
            #pragma unroll
            for (int k = 0; k < 16; ++k) M[base + k * 16] *= r;
        }
        __syncthreads();
    }
    if (t < 128) { int h = t >> 4, k = t & 15; M[h * 256 + k * 16 + k] = 0.f; }
    __syncthreads();
    for (int i = t; i < 2048; i += 256) G_out[i] = M[i];

    if (t < 128) {
        float s = 0.f;
        #pragma unroll
        for (int l = 0; l < 16; ++l) { float x = M[t * 16 + l]; s += x * x; }
        red[t] = s;
    }
    __syncthreads();
    if (t < 8) {
        float s = 0.f;
        for (int k = 0; k < 16; ++k) s += red[t * 16 + k];
        float inv = 1.f / fmaxf(sqrtf(s), 1e-8f);
        inv_nrm[t] = inv;
        hsq[t] = s * inv * inv;
    }
    __syncthreads();
    if (t == 0) {
        float tr = 0.f;
        for (int h = 0; h < 8; ++h) tr += hsq[h];
        trace_s = tr;
    }
    __syncthreads();
    float w = 0.f;
    #pragma unroll
    for (int h = 0; h < 8; ++h) w += M[h * 256 + t] * inv_nrm[h];
    red[t] = w * w;
    __syncthreads();
    for (int off = 128; off; off >>= 1) {
        if (t < off) red[t] += red[t + off];
        __syncthreads();
    }
    if (t == 0) out_reg[0] = 0.02f * (red[0] - trace_s) / 56.f;
}

// ---------------------------------------------------------------------------
// Kernel B: S = softmax(concat(desc,nv) @ W_eff^T + b_eff)  (wave per row)
// ---------------------------------------------------------------------------
__global__ void kB(const float* __restrict__ desc, const float* __restrict__ nv,
                   const float* __restrict__ W_eff, const float* __restrict__ b_eff,
                   float* __restrict__ S) {
    int row  = blockIdx.x * 4 + (threadIdx.x >> 6);
    int lane = threadIdx.x & 63;
    int k = lane & 15, q = lane >> 4;
    const float* x = (q < 2) ? (desc + (size_t)row * 256 + q * 128)
                             : (nv   + (size_t)row * 256 + (q - 2) * 128);
    const float4* x4 = (const float4*)x;
    const float4* w4 = (const float4*)(W_eff + k * 512 + q * 128);
    float acc = 0.f;
    #pragma unroll
    for (int i = 0; i < 32; ++i) {
        float4 a = x4[i], b = w4[i];
        acc += a.x * b.x + a.y * b.y + a.z * b.z + a.w * b.w;
    }
    acc += __shfl_xor(acc, 16);
    acc += __shfl_xor(acc, 32);
    float logit = acc + b_eff[k];
    float mx = logit;
    #pragma unroll
    for (int off = 8; off; off >>= 1) mx = fmaxf(mx, __shfl_xor(mx, off));
    float e = __expf(logit - mx);
    float s = e;
    #pragma unroll
    for (int off = 8; off; off >>= 1) s += __shfl_xor(s, off);
    if (q == 0) S[(size_t)row * 16 + k] = e / s;
}

// ---------------------------------------------------------------------------
// Kernel C: blocks 0..1023  -> affinity: blk>>2 = (b,h), blk&3 = 64-row slice
//           blocks 1024..1055 -> per-batch regularizers, atomicAdd into out_reg
//
// Key fact: S rows are softmax outputs (sum=1, entries in (0,1)) and sinkhorn-
// normalized G has entries <= 1, so x = 2*(S G)·S in [0,2].  Softmax/logsumexp
// are shift-invariant -> use M = 0: exp(x) in [1, e^2], L in [256, ~1892].
// No max pass needed; single dot pass with A held in registers.
// ---------------------------------------------------------------------------
__global__ __launch_bounds__(256, 4) void kC(const float* __restrict__ S,
                                             const float* __restrict__ G,
                                             float* __restrict__ bias,
                                             float* __restrict__ Q,
                                             float* __restrict__ out_reg) {
    __shared__ float Su[4096];      // S_b  [n][16] (unpadded; m-loop reads are
                                    // wave-uniform broadcast -> conflict-free)
    __shared__ float Gl[256];       // G_h  [k][l]
    __shared__ float Rl[64 * 20];   // 2*(S G) rows, stride 20 (pad: 8-way max)
    __shared__ float psum[256];     // per-(row, m-seg) partial L
    __shared__ float red[256];      // reg-branch scratch
    int t = threadIdx.x;
    int blk = blockIdx.x;

    if (blk >= 1024) {
        // ---- regularizer block for batch b ----
        int b = blk - 1024;
        for (int i = t; i < 4096; i += 256) Su[i] = S[(size_t)b * 4096 + i];
        __syncthreads();
        int k = t >> 4, l = t & 15;
        float s = 0.f;
        for (int n = 0; n < 256; ++n) s += Su[n * 16 + k] * Su[n * 16 + l];
        s *= (1.f / 256.f);
        red[t] = (k == l) ? 0.f : s * s;
        __syncthreads();
        for (int off = 128; off; off >>= 1) {
            if (t < off) red[t] += red[t + off];
            __syncthreads();
        }
        if (t < 16) {
            float u = 0.f;
            for (int n = 0; n < 256; ++n) u += Su[n * 16 + t];
            psum[t] = u * (1.f / 256.f);
        }
        __syncthreads();
        if (t == 0) {
            float su = 0.f;
            for (int kk = 0; kk < 16; ++kk) su += psum[kk];
            float kl = 0.f;
            for (int kk = 0; kk < 16; ++kk) {
                float uc = fmaxf(psum[kk] / (su + 1e-8f), 1e-8f);
                kl += uc * (logf(uc) - LOG_INV_K);
            }
            float val = 0.1f * red[0] / 8192.f + 0.1f * kl / 32.f;
            atomicAdd(out_reg, val);
        }
        return;
    }

    // ---- affinity ----
    int bh = blk >> 2, qq = blk & 3;
    int b = bh >> 3, h = bh & 7;
    int n0 = qq * 64;

    // stage S_b and G_h
    {
        const float4* Sg = (const float4*)(S + (size_t)b * 4096);
        float4* Su4 = (float4*)Su;
        for (int i = t; i < 1024; i += 256) Su4[i] = Sg[i];
        Gl[t] = G[h * 256 + t];
    }
    __syncthreads();

    // R[r][l] = 2 * sum_k S[n0+r][k] * G_h[k][l], computed once per block.
    // thread t -> r = t>>2, l-quad = (t&3)*4.  S row read from global (L2-hot).
    {
        int r = t >> 2, l4 = (t & 3) * 4;
        const float4* mp = (const float4*)(S + (size_t)b * 4096 + (size_t)(n0 + r) * 16);
        float4 s0 = mp[0], s1 = mp[1], s2 = mp[2], s3 = mp[3];
        float sr[16] = { s0.x,s0.y,s0.z,s0.w, s1.x,s1.y,s1.z,s1.w,
                         s2.x,s2.y,s2.z,s2.w, s3.x,s3.y,s3.z,s3.w };
        float a0 = 0.f, a1 = 0.f, a2 = 0.f, a3 = 0.f;
        #pragma unroll
        for (int k = 0; k < 16; ++k) {
            float4 g = *(const float4*)(Gl + k * 16 + l4);
            a0 += sr[k] * g.x; a1 += sr[k] * g.y;
            a2 += sr[k] * g.z; a3 += sr[k] * g.w;
        }
        float4 rv = make_float4(2.f * a0, 2.f * a1, 2.f * a2, 2.f * a3);
        *(float4*)(Rl + r * 20 + l4) = rv;
    }
    __syncthreads();

    // thread t: row r = t&63 (local), m-segment w = t>>6 (64 m's).
    int r = t & 63, w = t >> 6;
    float rv[16];
    {
        const float4* rp = (const float4*)(Rl + r * 20);
        float4 r0 = rp[0], r1 = rp[1], r2 = rp[2], r3 = rp[3];
        rv[0]=r0.x; rv[1]=r0.y; rv[2]=r0.z; rv[3]=r0.w;
        rv[4]=r1.x; rv[5]=r1.y; rv[6]=r1.z; rv[7]=r1.w;
        rv[8]=r2.x; rv[9]=r2.y; rv[10]=r2.z; rv[11]=r2.w;
        rv[12]=r3.x; rv[13]=r3.y; rv[14]=r3.z; rv[15]=r3.w;
    }

    int mbase = w * 64;
    float a[64];
    float ls = 0.f;
    #pragma unroll
    for (int j = 0; j < 64; ++j) {
        const float4* p = (const float4*)(Su + (mbase + j) * 16);   // broadcast
        float4 q0 = p[0], q1 = p[1], q2 = p[2], q3 = p[3];
        float x = rv[0]*q0.x + rv[1]*q0.y + rv[2]*q0.z + rv[3]*q0.w
                + rv[4]*q1.x + rv[5]*q1.y + rv[6]*q1.z + rv[7]*q1.w
                + rv[8]*q2.x + rv[9]*q2.y + rv[10]*q2.z + rv[11]*q2.w
                + rv[12]*q3.x + rv[13]*q3.y + rv[14]*q3.z + rv[15]*q3.w;
        a[j] = x;
        ls += __expf(x);
    }
    psum[t] = ls;
    __syncthreads();

    float L = psum[r] + psum[64 + r] + psum[128 + r] + psum[192 + r];
    float lnL = __logf(L);
    float rc = 1.f / L;

    size_t base = (size_t)bh * 65536 + (size_t)(n0 + r) * 256 + mbase;
    float4* Qp = (float4*)(Q + base);
    float4* Bp = (float4*)(bias + base);
    #pragma unroll
    for (int j4 = 0; j4 < 16; ++j4) {
        float4 qv, bv;
        qv.x = __expf(a[4*j4+0]) * rc;  bv.x = fmaxf(a[4*j4+0] - lnL, LOG_EPS);
        qv.y = __expf(a[4*j4+1]) * rc;  bv.y = fmaxf(a[4*j4+1] - lnL, LOG_EPS);
        qv.z = __expf(a[4*j4+2]) * rc;  bv.z = fmaxf(a[4*j4+2] - lnL, LOG_EPS);
        qv.w = __expf(a[4*j4+3]) * rc;  bv.w = fmaxf(a[4*j4+3] - lnL, LOG_EPS);
        Qp[j4] = qv;
        Bp[j4] = bv;
    }
}

// ---------------------------------------------------------------------------
extern "C" void kernel_launch(void* const* d_in, const int* in_sizes, int n_in,
                              void* d_out, int out_size, void* d_ws, size_t ws_size,
                              hipStream_t stream) {
    const float* desc     = (const float*)d_in[0];
    const float* nv       = (const float*)d_in[1];
    const float* W_fusion = (const float*)d_in[2];
    const float* b_fusion = (const float*)d_in[3];
    const float* W_slot   = (const float*)d_in[4];
    const float* b_slot   = (const float*)d_in[5];
    const float* G_param  = (const float*)d_in[6];

    float* out = (float*)d_out;
    float* out_bias = out;
    float* out_Q    = out + 16777216;
    float* out_reg  = out + 33554432;

    float* ws    = (float*)d_ws;
    float* W_eff = ws;           // 8192
    float* b_eff = ws + 8192;    // 16
    float* G_out = ws + 8208;    // 2048
    float* S     = ws + 10256;   // 131072

    kA<<<33, 256, 0, stream>>>(W_fusion, b_fusion, W_slot, b_slot, G_param,
                               W_eff, b_eff, G_out, out_reg);
    kB<<<2048, 256, 0, stream>>>(desc, nv, W_eff, b_eff, S);
    kC<<<1056, 256, 0, stream>>>(S, G_out, out_bias, out_Q, out_reg);
}

// Round 4
// 236.248 us; speedup vs baseline: 1.5039x; 1.5039x over previous
//
#include <hip/hip_runtime.h>
#include <math.h>

#define LOG_EPS   (-18.420680743952367f)   // ln(1e-8)
#define LOG_INV_K (-2.772588722239781f)    // ln(1/16)

// ---------------------------------------------------------------------------
// Kernel A: blocks 0..31 -> W_eff = W_slot @ W_fusion, b_eff
//           block  32    -> G softmax+sinkhorn+zero-diag + Frobenius reg
// ---------------------------------------------------------------------------
__global__ void kA(const float* __restrict__ W_fusion, const float* __restrict__ b_fusion,
                   const float* __restrict__ W_slot,   const float* __restrict__ b_slot,
                   const float* __restrict__ G_param,
                   float* __restrict__ W_eff, float* __restrict__ b_eff,
                   float* __restrict__ G_out, float* __restrict__ out_reg) {
    int t = threadIdx.x;
    if (blockIdx.x < 32) {
        int idx = blockIdx.x * 256 + t;          // 0..8191
        int k = idx >> 9, j = idx & 511;
        const float* ws = W_slot + k * 256;
        float s = 0.f;
        #pragma unroll 4
        for (int d = 0; d < 256; ++d) s += ws[d] * W_fusion[d * 512 + j];
        W_eff[idx] = s;
        if (idx < 16) {
            float bb = b_slot[idx];
            for (int d = 0; d < 256; ++d) bb += W_slot[idx * 256 + d] * b_fusion[d];
            b_eff[idx] = bb;
        }
        return;
    }
    // ---- G block ----
    __shared__ float M[2048];
    __shared__ float red[256];
    __shared__ float inv_nrm[8];
    __shared__ float hsq[8];
    __shared__ float trace_s;

    if (t < 128) {
        int base = t * 16;
        float v[16]; float mx = -1e30f;
        #pragma unroll
        for (int l = 0; l < 16; ++l) { v[l] = G_param[base + l]; mx = fmaxf(mx, v[l]); }
        float s = 0.f;
        #pragma unroll
        for (int l = 0; l < 16; ++l) { v[l] = expf(v[l] - mx); s += v[l]; }
        float r = 1.f / s;
        #pragma unroll
        for (int l = 0; l < 16; ++l) M[base + l] = fmaxf(v[l] * r, 1e-6f);
    }
    __syncthreads();
    for (int it = 0; it < 10; ++it) {
        if (t < 128) {
            float s = 0.f;
            #pragma unroll
            for (int l = 0; l < 16; ++l) s += M[t * 16 + l];
            float r = 1.f / (s + 1e-6f);
            #pragma unroll
            for (int l = 0; l < 16; ++l) M[t * 16 + l] *= r;
        }
        __syncthreads();
        if (t < 128) {
            int h = t >> 4, l = t & 15, base = h * 256 + l;
            float s = 0.f;
            #pragma unroll
            for (int k = 0; k < 16; ++k) s += M[base + k * 16];
            float r = 1.f / (s + 1e-6f);
            #pragma unroll
            for (int k = 0; k < 16; ++k) M[base + k * 16] *= r;
        }
        __syncthreads();
    }
    if (t < 128) { int h = t >> 4, k = t & 15; M[h * 256 + k * 16 + k] = 0.f; }
    __syncthreads();
    for (int i = t; i < 2048; i += 256) G_out[i] = M[i];

    if (t < 128) {
        float s = 0.f;
        #pragma unroll
        for (int l = 0; l < 16; ++l) { float x = M[t * 16 + l]; s += x * x; }
        red[t] = s;
    }
    __syncthreads();
    if (t < 8) {
        float s = 0.f;
        for (int k = 0; k < 16; ++k) s += red[t * 16 + k];
        float inv = 1.f / fmaxf(sqrtf(s), 1e-8f);
        inv_nrm[t] = inv;
        hsq[t] = s * inv * inv;
    }
    __syncthreads();
    if (t == 0) {
        float tr = 0.f;
        for (int h = 0; h < 8; ++h) tr += hsq[h];
        trace_s = tr;
    }
    __syncthreads();
    float w = 0.f;
    #pragma unroll
    for (int h = 0; h < 8; ++h) w += M[h * 256 + t] * inv_nrm[h];
    red[t] = w * w;
    __syncthreads();
    for (int off = 128; off; off >>= 1) {
        if (t < off) red[t] += red[t + off];
        __syncthreads();
    }
    if (t == 0) out_reg[0] = 0.02f * (red[0] - trace_s) / 56.f;
}

// ---------------------------------------------------------------------------
// Kernel B: S = softmax(concat(desc,nv) @ W_eff^T + b_eff)  (wave per row)
// ---------------------------------------------------------------------------
__global__ void kB(const float* __restrict__ desc, const float* __restrict__ nv,
                   const float* __restrict__ W_eff, const float* __restrict__ b_eff,
                   float* __restrict__ S) {
    int row  = blockIdx.x * 4 + (threadIdx.x >> 6);
    int lane = threadIdx.x & 63;
    int k = lane & 15, q = lane >> 4;
    const float* x = (q < 2) ? (desc + (size_t)row * 256 + q * 128)
                             : (nv   + (size_t)row * 256 + (q - 2) * 128);
    const float4* x4 = (const float4*)x;
    const float4* w4 = (const float4*)(W_eff + k * 512 + q * 128);
    float acc = 0.f;
    #pragma unroll
    for (int i = 0; i < 32; ++i) {
        float4 a = x4[i], b = w4[i];
        acc += a.x * b.x + a.y * b.y + a.z * b.z + a.w * b.w;
    }
    acc += __shfl_xor(acc, 16);
    acc += __shfl_xor(acc, 32);
    float logit = acc + b_eff[k];
    float mx = logit;
    #pragma unroll
    for (int off = 8; off; off >>= 1) mx = fmaxf(mx, __shfl_xor(mx, off));
    float e = __expf(logit - mx);
    float s = e;
    #pragma unroll
    for (int off = 8; off; off >>= 1) s += __shfl_xor(s, off);
    if (q == 0) S[(size_t)row * 16 + k] = e / s;
}

// ---------------------------------------------------------------------------
// Kernel C: blocks 0..1023  -> affinity: blk>>2 = (b,h), blk&3 = 64-row slice
//           blocks 1024..1055 -> per-batch regularizers, atomicAdd into out_reg
//
// x = 2*(S G)·S  in [0,2]  (S rows are softmax outputs; sinkhorn G entries <=1)
// -> logsumexp with shift 0: no max pass.  exp computed ONCE per element.
// Store layout: thread t -> columns 4*(t&63)..+3 of rows r = (t>>6) mod 4
// (adjacent lanes adjacent addresses -> wave writes 1 KB contiguous; round-3's
// per-lane-contiguous layout caused 2.4x WRITE_SIZE amplification).
// S staged TRANSPOSED in LDS (stride 260) so column reads are the standard
// lanes-read-consecutive-float4 conflict-free pattern.
// ---------------------------------------------------------------------------
__global__ __launch_bounds__(256) void kC(const float* __restrict__ S,
                                          const float* __restrict__ G,
                                          float* __restrict__ bias,
                                          float* __restrict__ Q,
                                          float* __restrict__ out_reg) {
    __shared__ float smem[5696];    // 22.8 KB, overlaid per branch
    int t = threadIdx.x;
    int blk = blockIdx.x;

    if (blk >= 1024) {
        // ---- regularizer block for batch b ----
        float* Su  = smem;          // [256][16]
        float* red = smem + 4096;   // [256]
        float* ps  = smem + 4352;   // [16]
        int b = blk - 1024;
        for (int i = t; i < 4096; i += 256) Su[i] = S[(size_t)b * 4096 + i];
        __syncthreads();
        int k = t >> 4, l = t & 15;
        float s = 0.f;
        for (int n = 0; n < 256; ++n) s += Su[n * 16 + k] * Su[n * 16 + l];
        s *= (1.f / 256.f);
        red[t] = (k == l) ? 0.f : s * s;
        __syncthreads();
        for (int off = 128; off; off >>= 1) {
            if (t < off) red[t] += red[t + off];
            __syncthreads();
        }
        if (t < 16) {
            float u = 0.f;
            for (int n = 0; n < 256; ++n) u += Su[n * 16 + t];
            ps[t] = u * (1.f / 256.f);
        }
        __syncthreads();
        if (t == 0) {
            float su = 0.f;
            for (int kk = 0; kk < 16; ++kk) su += ps[kk];
            float kl = 0.f;
            for (int kk = 0; kk < 16; ++kk) {
                float uc = fmaxf(ps[kk] / (su + 1e-8f), 1e-8f);
                kl += uc * (logf(uc) - LOG_INV_K);
            }
            float val = 0.1f * red[0] / 8192.f + 0.1f * kl / 32.f;
            atomicAdd(out_reg, val);
        }
        return;
    }

    // ---- affinity ----
    float* St = smem;               // [16][260]  S_b transposed, padded
    float* Rl = smem + 4160;        // [64][20]   2*(S G) rows for this slice
    float* Gl = smem + 5440;        // [16][16]
    int bh = blk >> 2, qq = blk & 3;
    int b = bh >> 3, h = bh & 7;
    int n0 = qq * 64;

    // stage: S_b transposed + G_h
    {
        const float4* Sg = (const float4*)(S + (size_t)b * 4096);
        for (int i = t; i < 1024; i += 256) {
            int row = i >> 2, q = i & 3;
            float4 v = Sg[i];
            St[(4 * q + 0) * 260 + row] = v.x;
            St[(4 * q + 1) * 260 + row] = v.y;
            St[(4 * q + 2) * 260 + row] = v.z;
            St[(4 * q + 3) * 260 + row] = v.w;
        }
        Gl[t] = G[h * 256 + t];
    }
    __syncthreads();

    // R[r][l] = 2 * sum_k S[n0+r][k] * G_h[k][l]; thread t -> r=t>>2, l4=(t&3)*4
    {
        int r = t >> 2, l4 = (t & 3) * 4;
        const float4* mp = (const float4*)(S + (size_t)b * 4096 + (size_t)(n0 + r) * 16);
        float4 s0 = mp[0], s1 = mp[1], s2 = mp[2], s3 = mp[3];
        float sr[16] = { s0.x,s0.y,s0.z,s0.w, s1.x,s1.y,s1.z,s1.w,
                         s2.x,s2.y,s2.z,s2.w, s3.x,s3.y,s3.z,s3.w };
        float a0 = 0.f, a1 = 0.f, a2 = 0.f, a3 = 0.f;
        #pragma unroll
        for (int k = 0; k < 16; ++k) {
            float4 g = *(const float4*)(Gl + k * 16 + l4);
            a0 += sr[k] * g.x; a1 += sr[k] * g.y;
            a2 += sr[k] * g.z; a3 += sr[k] * g.w;
        }
        *(float4*)(Rl + r * 20 + l4) = make_float4(2.f*a0, 2.f*a1, 2.f*a2, 2.f*a3);
    }
    __syncthreads();

    // main: cg = t&63 -> columns 4cg..4cg+3; wave rs = t>>6 -> rows rs, rs+4, ...
    int cg = t & 63, rs = t >> 6;
    float sr[4][16];                       // S rows of my 4 columns
    #pragma unroll
    for (int k = 0; k < 16; ++k) {
        float4 v = *(const float4*)(St + k * 260 + 4 * cg);   // conflict-free b128
        sr[0][k] = v.x; sr[1][k] = v.y; sr[2][k] = v.z; sr[3][k] = v.w;
    }
    size_t obase = (size_t)bh * 65536 + (size_t)n0 * 256 + 4 * cg;
    for (int r = rs; r < 64; r += 4) {
        const float4* rp = (const float4*)(Rl + r * 20);      // wave-uniform bcast
        float4 r0 = rp[0], r1 = rp[1], r2 = rp[2], r3 = rp[3];
        float rv[16] = { r0.x,r0.y,r0.z,r0.w, r1.x,r1.y,r1.z,r1.w,
                         r2.x,r2.y,r2.z,r2.w, r3.x,r3.y,r3.z,r3.w };
        float x[4], e[4];
        #pragma unroll
        for (int j = 0; j < 4; ++j) {
            float a = 0.f;
            #pragma unroll
            for (int l = 0; l < 16; ++l) a += rv[l] * sr[j][l];
            x[j] = a;
            e[j] = __expf(a);
        }
        float ls = (e[0] + e[1]) + (e[2] + e[3]);
        #pragma unroll
        for (int off = 1; off < 64; off <<= 1) ls += __shfl_xor(ls, off);
        float lnL = __logf(ls);
        float rc = 1.f / ls;
        size_t ro = obase + (size_t)r * 256;
        *(float4*)(Q + ro)    = make_float4(e[0]*rc, e[1]*rc, e[2]*rc, e[3]*rc);
        *(float4*)(bias + ro) = make_float4(fmaxf(x[0]-lnL, LOG_EPS),
                                            fmaxf(x[1]-lnL, LOG_EPS),
                                            fmaxf(x[2]-lnL, LOG_EPS),
                                            fmaxf(x[3]-lnL, LOG_EPS));
    }
}

// ---------------------------------------------------------------------------
extern "C" void kernel_launch(void* const* d_in, const int* in_sizes, int n_in,
                              void* d_out, int out_size, void* d_ws, size_t ws_size,
                              hipStream_t stream) {
    const float* desc     = (const float*)d_in[0];
    const float* nv       = (const float*)d_in[1];
    const float* W_fusion = (const float*)d_in[2];
    const float* b_fusion = (const float*)d_in[3];
    const float* W_slot   = (const float*)d_in[4];
    const float* b_slot   = (const float*)d_in[5];
    const float* G_param  = (const float*)d_in[6];

    float* out = (float*)d_out;
    float* out_bias = out;
    float* out_Q    = out + 16777216;
    float* out_reg  = out + 33554432;

    float* ws    = (float*)d_ws;
    float* W_eff = ws;           // 8192
    float* b_eff = ws + 8192;    // 16
    float* G_out = ws + 8208;    // 2048
    float* S     = ws + 10256;   // 131072

    kA<<<33, 256, 0, stream>>>(W_fusion, b_fusion, W_slot, b_slot, G_param,
                               W_eff, b_eff, G_out, out_reg);
    kB<<<2048, 256, 0, stream>>>(desc, nv, W_eff, b_eff, S);
    kC<<<1056, 256, 0, stream>>>(S, G_out, out_bias, out_Q, out_reg);
}